// Round 4
// baseline (164.200 us; speedup 1.0000x reference)
//
#include <hip/hip_runtime.h>

// CausalSelfAttention: B=4, T=2048, D=1024, DA=256, fp32 in/out.
// Pipeline: prep (convert+transpose), QKV GEMMs, scores->bf16 E + partial
// row-sums, PV GEMM (inv computed inline), finalize (normalized fp32 W).
// All MFMA kernels: 2-phase double-buffered global_load_lds pipeline
// (issue next K-tile before computing current; single barrier per K-step).

typedef short bf16x8 __attribute__((ext_vector_type(8)));   // 8 bf16 in 4 VGPRs
typedef float f32x4  __attribute__((ext_vector_type(4)));
typedef unsigned int  u32x4 __attribute__((ext_vector_type(4)));
typedef unsigned short u16x4 __attribute__((ext_vector_type(4)));

static __device__ __forceinline__ unsigned short f2bf(float f) {
    union { float f; unsigned int u; } v; v.f = f;
    unsigned int u = v.u;
    return (unsigned short)((u + 0x7FFFu + ((u >> 16) & 1u)) >> 16);  // RNE
}

// async global->LDS, 16B per lane; LDS dest must be wave-linear (lane*16).
#define GLL(g, l) __builtin_amdgcn_global_load_lds( \
    (const __attribute__((address_space(1))) void*)(g), \
    (__attribute__((address_space(3))) void*)(l), 16, 0, 0)

// ---------------- prep: x->bf16 + 3 weight transposes, one launch ----------------

__global__ __launch_bounds__(256) void prep(
    const float* __restrict__ x, const float* __restrict__ Wq,
    const float* __restrict__ Wk, const float* __restrict__ Wv,
    unsigned short* __restrict__ x_bf, unsigned short* __restrict__ Wqk_t,
    unsigned short* __restrict__ Wv_t)
{
    int bid = blockIdx.x, tid = threadIdx.x;
    if (bid < 8192) {           // convert x: 8192*256 threads * 4 elems
        int i = bid * 256 + tid;
        f32x4 v = ((const f32x4*)x)[i];
        u16x4 o;
        o[0] = f2bf(v[0]); o[1] = f2bf(v[1]); o[2] = f2bf(v[2]); o[3] = f2bf(v[3]);
        ((u16x4*)x_bf)[i] = o;
        return;
    }
    // transpose-convert W[K=1024][N] -> Wt[N][1024], scaled
    const float* W; unsigned short* Wt; int N, lb; float scale;
    if (bid < 8448)      { W = Wq; Wt = Wqk_t;              N = 256;  lb = bid - 8192; scale = 1.f / 16.f; }
    else if (bid < 8704) { W = Wk; Wt = Wqk_t + 256 * 1024; N = 256;  lb = bid - 8448; scale = 1.f; }
    else                 { W = Wv; Wt = Wv_t;               N = 1024; lb = bid - 8704; scale = 1.f; }
    int nb = N >> 5;
    int n0 = (lb % nb) * 32, k0 = (lb / nb) * 32;
    int tx = tid & 31, ty = tid >> 5;   // 32 x 8
    __shared__ float tile[32][33];
#pragma unroll
    for (int r = 0; r < 4; ++r)
        tile[ty + 8 * r][tx] = W[(size_t)(k0 + ty + 8 * r) * N + n0 + tx];
    __syncthreads();
#pragma unroll
    for (int r = 0; r < 4; ++r)
        Wt[(size_t)(n0 + ty + 8 * r) * 1024 + k0 + tx] = f2bf(tile[tx][ty + 8 * r] * scale);
}

// ---------------- GEMM (A[M,K] @ Bt[N,K]^T), bf16 in, bf16 out, 2-phase ----------------

#define BM 128
#define BN 128
#define BK 64

__global__ __launch_bounds__(256) void gemm_bt_bf16(
    const unsigned short* __restrict__ A, int lda,
    const unsigned short* __restrict__ Bt, int ldb,
    unsigned short* __restrict__ C, int ldc, int K)
{
    __shared__ __align__(16) unsigned short As[2][BM][BK];
    __shared__ __align__(16) unsigned short Bs[2][BM][BK];
    int tid = threadIdx.x;
    int m0 = blockIdx.y * BM, n0 = blockIdx.x * BN;
    int lane = tid & 63, wave = tid >> 6;
    int wr = (wave >> 1) * 64, wc = (wave & 1) * 64;
    int fr = lane & 15, fk = (lane >> 4) * 8;
    int srow = tid >> 3, scol = (tid & 7) * 8;
    f32x4 acc[4][4] = {};
    int nt = K / BK;

    const unsigned short* Ab = A + (size_t)(m0 + srow) * lda + scol;
    const unsigned short* Bb = Bt + (size_t)(n0 + srow) * ldb + scol;

#define STAGE_G(t, p) { \
    const unsigned short* Ap = Ab + (t) * BK; \
    const unsigned short* Bp = Bb + (t) * BK; \
    _Pragma("unroll") \
    for (int i = 0; i < 4; ++i) { \
        GLL(Ap + (size_t)32 * i * lda, &As[p][srow + 32 * i][scol]); \
        GLL(Bp + (size_t)32 * i * ldb, &Bs[p][srow + 32 * i][scol]); \
    } }

    STAGE_G(0, 0);
    __syncthreads();
    for (int t = 0; t < nt; ++t) {
        int p = t & 1;
        if (t + 1 < nt) STAGE_G(t + 1, p ^ 1);
#pragma unroll
        for (int ks = 0; ks < BK; ks += 32) {
            bf16x8 af[4], bfr[4];
#pragma unroll
            for (int i = 0; i < 4; ++i) af[i]  = *(const bf16x8*)(&As[p][wr + 16 * i + fr][ks + fk]);
#pragma unroll
            for (int j = 0; j < 4; ++j) bfr[j] = *(const bf16x8*)(&Bs[p][wc + 16 * j + fr][ks + fk]);
#pragma unroll
            for (int i = 0; i < 4; ++i)
#pragma unroll
                for (int j = 0; j < 4; ++j)
                    acc[i][j] = __builtin_amdgcn_mfma_f32_16x16x32_bf16(af[i], bfr[j], acc[i][j], 0, 0, 0);
        }
        __syncthreads();
    }
#pragma unroll
    for (int i = 0; i < 4; ++i)
#pragma unroll
        for (int j = 0; j < 4; ++j)
#pragma unroll
            for (int r = 0; r < 4; ++r) {
                int row = m0 + wr + 16 * i + (lane >> 4) * 4 + r;
                int col = n0 + wc + 16 * j + fr;
                C[(size_t)row * ldc + col] = f2bf(acc[i][j][r]);
            }
}

// ---------------- scores: E = exp(Q Kt^T) bf16 + partial row sums, 2-phase ----------------
// QK buffer: [8192][512] bf16, Q = cols 0:256, K = cols 256:512.
// Live (causal) tiles only: 544 blocks, XCD-bijective swizzle (544 = 8*68).

__global__ __launch_bounds__(256) void scores_e(
    const unsigned short* __restrict__ QK, unsigned short* __restrict__ Ebf,
    float* __restrict__ partials)
{
    int lin = blockIdx.x;                     // 0..543
    int swz = (lin & 7) * 68 + (lin >> 3);
    int b = swz / 136, t = swz - b * 136;
    int y = (int)floorf((sqrtf(8.f * (float)t + 1.f) - 1.f) * 0.5f);
    if ((y + 1) * (y + 2) / 2 <= t) ++y;
    if (y * (y + 1) / 2 > t) --y;
    int x = t - y * (y + 1) / 2;
    int m0 = y * 128, n0 = x * 128;

    const unsigned short* A  = QK + (size_t)b * 2048 * 512;
    const unsigned short* Bt = A + 256;
    unsigned short* Eb = Ebf + (size_t)b * 2048 * 2048;

    __shared__ __align__(16) unsigned short As[2][128][64];
    __shared__ __align__(16) unsigned short Bs[2][128][64];
    __shared__ float rowsum2[2][128];
    int tid = threadIdx.x;
    int lane = tid & 63, wave = tid >> 6;
    int wr = (wave >> 1) * 64, wc = (wave & 1) * 64;
    int fr = lane & 15, fk = (lane >> 4) * 8;
    int srow = tid >> 3, scol = (tid & 7) * 8;
    f32x4 acc[4][4] = {};

    const unsigned short* Ab = A  + (size_t)(m0 + srow) * 512 + scol;
    const unsigned short* Bb = Bt + (size_t)(n0 + srow) * 512 + scol;

#define STAGE_S(t, p) { \
    const unsigned short* Ap = Ab + (t) * 64; \
    const unsigned short* Bp = Bb + (t) * 64; \
    _Pragma("unroll") \
    for (int i = 0; i < 4; ++i) { \
        GLL(Ap + (size_t)32 * i * 512, &As[p][srow + 32 * i][scol]); \
        GLL(Bp + (size_t)32 * i * 512, &Bs[p][srow + 32 * i][scol]); \
    } }

    STAGE_S(0, 0);
    __syncthreads();
#pragma unroll
    for (int tt = 0; tt < 4; ++tt) {
        int p = tt & 1;
        if (tt < 3) STAGE_S(tt + 1, p ^ 1);
#pragma unroll
        for (int ks = 0; ks < 64; ks += 32) {
            bf16x8 af[4], bfr[4];
#pragma unroll
            for (int i = 0; i < 4; ++i) af[i]  = *(const bf16x8*)(&As[p][wr + 16 * i + fr][ks + fk]);
#pragma unroll
            for (int j = 0; j < 4; ++j) bfr[j] = *(const bf16x8*)(&Bs[p][wc + 16 * j + fr][ks + fk]);
#pragma unroll
            for (int i = 0; i < 4; ++i)
#pragma unroll
                for (int j = 0; j < 4; ++j)
                    acc[i][j] = __builtin_amdgcn_mfma_f32_16x16x32_bf16(af[i], bfr[j], acc[i][j], 0, 0, 0);
        }
        __syncthreads();
    }

    // exp + mask + bf16 store + per-row partial sums
#pragma unroll
    for (int i = 0; i < 4; ++i)
#pragma unroll
        for (int r = 0; r < 4; ++r) {
            int q = m0 + wr + 16 * i + (lane >> 4) * 4 + r;
            float s = 0.f;
#pragma unroll
            for (int j = 0; j < 4; ++j) {
                int k = n0 + wc + 16 * j + fr;
                float e = (k <= q) ? __expf(acc[i][j][r]) : 0.f;
                Eb[(size_t)q * 2048 + k] = f2bf(e);
                s += e;
            }
            s += __shfl_xor(s, 1, 64); s += __shfl_xor(s, 2, 64);
            s += __shfl_xor(s, 4, 64); s += __shfl_xor(s, 8, 64);
            if (fr == 0) rowsum2[wave & 1][wr + 16 * i + (lane >> 4) * 4 + r] = s;
        }
    __syncthreads();
    if (tid < 128)
        partials[((size_t)b * 2048 + m0 + tid) * 16 + x] =
            rowsum2[0][tid] + rowsum2[1][tid];
}

// ---------------- finalize: W = E*inv (fp32, zeros above diag) ----------------

__global__ __launch_bounds__(256) void finalize_w(
    const unsigned short* __restrict__ Ebf, const float* __restrict__ partials,
    float* __restrict__ Wout)
{
    int r = blockIdx.x, q = r & 2047, tid = threadIdx.x;
    __shared__ float invs;
    if (tid < 64) {
        int nt = q >> 7;
        float p = (tid <= nt) ? partials[(size_t)r * 16 + tid] : 0.f;
        p += __shfl_xor(p, 1, 64); p += __shfl_xor(p, 2, 64);
        p += __shfl_xor(p, 4, 64); p += __shfl_xor(p, 8, 64);
        if (tid == 0) invs = 1.f / p;
    }
    __syncthreads();
    float iv = invs;
    const unsigned short* er = Ebf + (size_t)r * 2048;
    float* wrow = Wout + (size_t)r * 2048;
    int c0 = tid * 8;
    f32x4 o0 = {}, o1 = {};
    if (c0 <= q) {   // masked entries within the chunk are exact bf16 zeros
        bf16x8 e = *(const bf16x8*)(er + c0);
#pragma unroll
        for (int j = 0; j < 4; ++j) {
            union { unsigned int u; float f; } a, bb;
            a.u = ((unsigned int)(unsigned short)e[j]) << 16;
            bb.u = ((unsigned int)(unsigned short)e[j + 4]) << 16;
            o0[j] = a.f * iv; o1[j] = bb.f * iv;
        }
    }
    *((f32x4*)wrow + 2 * tid) = o0;
    *((f32x4*)wrow + 2 * tid + 1) = o1;
}

// ---------------- PV: O = (E @ V) * inv, causal k-limit, 2-phase, XCD-balanced ----------------

__global__ __launch_bounds__(256) void gemm_pv(
    const unsigned short* __restrict__ P, const unsigned short* __restrict__ Vt,
    const float* __restrict__ partials, float* __restrict__ O)
{
    int lin = blockIdx.x;
    int j   = lin & 7;        // target XCD
    int idx = lin >> 3;       // 0..63
    int x   = idx & 7;        // col tile
    int h   = idx >> 3;       // 0..7
    int b   = h >> 1;         // batch
    int y   = (h & 1) ? j : 15 - j;   // row tile (balanced causal work)

    int m0 = y * BM, n0 = x * BN;
    const unsigned short* Pb = P + (size_t)b * 2048 * 2048;
    const unsigned short* Bt = Vt + (size_t)b * 2048;   // ldb = 8192
    float* Ob = O + (size_t)b * 2048 * 1024;
    int nt = (y + 1) * 2;     // Klim / BK

    __shared__ __align__(16) unsigned short As[2][BM][BK];
    __shared__ __align__(16) unsigned short Bs[2][BM][BK];
    __shared__ float invsh[128];
    int tid = threadIdx.x;
    int lane = tid & 63, wave = tid >> 6;
    int wr = (wave >> 1) * 64, wc = (wave & 1) * 64;
    int fr = lane & 15, fk = (lane >> 4) * 8;
    int srow = tid >> 3, scol = (tid & 7) * 8;
    f32x4 acc[4][4] = {};

    const unsigned short* Ab = Pb + (size_t)(m0 + srow) * 2048 + scol;
    const unsigned short* Bb = Bt + (size_t)(n0 + srow) * 8192 + scol;

#define STAGE_P(t, p) { \
    const unsigned short* Ap = Ab + (t) * BK; \
    const unsigned short* Bp = Bb + (t) * BK; \
    _Pragma("unroll") \
    for (int i = 0; i < 4; ++i) { \
        GLL(Ap + (size_t)32 * i * 2048, &As[p][srow + 32 * i][scol]); \
        GLL(Bp + (size_t)32 * i * 8192, &Bs[p][srow + 32 * i][scol]); \
    } }

    // per-row 1/sum from partials (y+1 live tiles per row, uniform in block)
    if (tid < 128) {
        const float* pp = partials + ((size_t)b * 2048 + m0 + tid) * 16;
        float s = 0.f;
        for (int i = 0; i <= y; ++i) s += pp[i];
        invsh[tid] = 1.f / s;
    }

    STAGE_P(0, 0);
    __syncthreads();
    for (int t = 0; t < nt; ++t) {
        int p = t & 1;
        if (t + 1 < nt) STAGE_P(t + 1, p ^ 1);
#pragma unroll
        for (int ks = 0; ks < BK; ks += 32) {
            bf16x8 af[4], bfr[4];
#pragma unroll
            for (int i = 0; i < 4; ++i) af[i]  = *(const bf16x8*)(&As[p][wr + 16 * i + fr][ks + fk]);
#pragma unroll
            for (int jj = 0; jj < 4; ++jj) bfr[jj] = *(const bf16x8*)(&Bs[p][wc + 16 * jj + fr][ks + fk]);
#pragma unroll
            for (int i = 0; i < 4; ++i)
#pragma unroll
                for (int jj = 0; jj < 4; ++jj)
                    acc[i][jj] = __builtin_amdgcn_mfma_f32_16x16x32_bf16(af[i], bfr[jj], acc[i][jj], 0, 0, 0);
        }
        __syncthreads();
    }
#pragma unroll
    for (int i = 0; i < 4; ++i)
#pragma unroll
        for (int r = 0; r < 4; ++r) {
            int rloc = wr + 16 * i + (lane >> 4) * 4 + r;
            int row = m0 + rloc;
            float iv = invsh[rloc];
#pragma unroll
            for (int jj = 0; jj < 4; ++jj) {
                int col = n0 + wc + 16 * jj + fr;
                Ob[(size_t)row * 1024 + col] = acc[i][jj][r] * iv;
            }
        }
}

// ---------------- launcher ----------------

extern "C" void kernel_launch(void* const* d_in, const int* in_sizes, int n_in,
                              void* d_out, int out_size, void* d_ws, size_t ws_size,
                              hipStream_t stream) {
    (void)in_sizes; (void)n_in; (void)out_size; (void)ws_size;
    const float* x  = (const float*)d_in[0];
    const float* Wq = (const float*)d_in[1];
    const float* Wk = (const float*)d_in[2];
    const float* Wv = (const float*)d_in[3];
    const int B = 4, T = 2048, D = 1024;
    const int M = B * T;  // 8192

    char* ws = (char*)d_ws;
    size_t off = 0;
    auto alloc = [&](size_t bytes) {
        void* p = ws + off; off += (bytes + 255) & ~(size_t)255; return p;
    };
    unsigned short* x_bf  = (unsigned short*)alloc((size_t)M * D * 2);
    unsigned short* Wqk_t = (unsigned short*)alloc((size_t)512 * D * 2);
    unsigned short* Wv_t  = (unsigned short*)alloc((size_t)D * D * 2);
    unsigned short* QK_bf = (unsigned short*)alloc((size_t)M * 512 * 2);
    unsigned short* Vt_bf = (unsigned short*)alloc((size_t)D * M * 2);
    unsigned short* E_bf  = (unsigned short*)alloc((size_t)M * T * 2);
    float*          parts = (float*)alloc((size_t)M * 16 * 4);

    float* outO = (float*)d_out;                       // [4][2048][1024]
    float* outW = (float*)d_out + (size_t)M * D;       // [4][2048][2048]

    // 1. prep: x->bf16 + 3 weight transposes (one launch)
    prep<<<dim3(8192 + 256 + 256 + 1024), 256, 0, stream>>>(
        x, Wq, Wk, Wv, x_bf, Wqk_t, Wv_t);

    // 2. QK-concat GEMM: [8192 x 512] = x_bf @ Wqk_t^T
    gemm_bt_bf16<<<dim3(512 / BN, M / BM), 256, 0, stream>>>(x_bf, D, Wqk_t, D, QK_bf, 512, D);
    // 2b. V^T GEMM: [1024 x 8192] = Wv_t @ x_bf^T
    gemm_bt_bf16<<<dim3(M / BN, D / BM), 256, 0, stream>>>(Wv_t, D, x_bf, D, Vt_bf, M, D);

    // 3. scores -> bf16 E (unnormalized) + partial row sums (live tiles only)
    scores_e<<<dim3(544), 256, 0, stream>>>(QK_bf, E_bf, parts);

    // 4. PV GEMM on unnormalized E, inline inv, scale in epilogue
    gemm_pv<<<dim3(512), 256, 0, stream>>>(E_bf, Vt_bf, parts, outO);

    // 5. finalize: normalized fp32 W to d_out (incl. zeros above diagonal)
    finalize_w<<<dim3(M), 256, 0, stream>>>(E_bf, parts, outW);
}

// Round 5
// 127.407 us; speedup vs baseline: 1.2888x; 1.2888x over previous
//
#include <hip/hip_runtime.h>

// CausalSelfAttention: B=4, T=2048, D=1024, DA=256, fp32 in/out.
// Pipeline: prep (convert+transpose), QKV GEMMs, scores->bf16 E + partial
// row-sums, PV GEMM (inv inline), finalize (normalized fp32 W).
// MFMA kernels: 2-buffer counted-vmcnt pipeline (T4: vmcnt(8), never drain
// mid-loop) + T2 source-pre-swizzled LDS (linear dest for global_load_lds,
// XOR-slot on read) to cut the 16-way ds_read bank conflict to 8-way.

typedef short bf16x8 __attribute__((ext_vector_type(8)));   // 8 bf16 in 4 VGPRs
typedef float f32x4  __attribute__((ext_vector_type(4)));
typedef unsigned int  u32x4 __attribute__((ext_vector_type(4)));
typedef unsigned short u16x4 __attribute__((ext_vector_type(4)));

static __device__ __forceinline__ unsigned short f2bf(float f) {
    union { float f; unsigned int u; } v; v.f = f;
    unsigned int u = v.u;
    return (unsigned short)((u + 0x7FFFu + ((u >> 16) & 1u)) >> 16);  // RNE
}

// async global->LDS, 16B per lane; LDS dest must be wave-linear (lane*16).
#define GLL(g, l) __builtin_amdgcn_global_load_lds( \
    (const __attribute__((address_space(1))) void*)(g), \
    (__attribute__((address_space(3))) void*)(l), 16, 0, 0)

#define BAR() __builtin_amdgcn_s_barrier()
#define VM8() asm volatile("s_waitcnt vmcnt(8)" ::: "memory")
#define VM0() asm volatile("s_waitcnt vmcnt(0)" ::: "memory")

// ---------------- prep: x->bf16 + 3 weight transposes, one launch ----------------

__global__ __launch_bounds__(256) void prep(
    const float* __restrict__ x, const float* __restrict__ Wq,
    const float* __restrict__ Wk, const float* __restrict__ Wv,
    unsigned short* __restrict__ x_bf, unsigned short* __restrict__ Wqk_t,
    unsigned short* __restrict__ Wv_t)
{
    int bid = blockIdx.x, tid = threadIdx.x;
    if (bid < 8192) {           // convert x: 8192*256 threads * 4 elems
        int i = bid * 256 + tid;
        f32x4 v = ((const f32x4*)x)[i];
        u16x4 o;
        o[0] = f2bf(v[0]); o[1] = f2bf(v[1]); o[2] = f2bf(v[2]); o[3] = f2bf(v[3]);
        ((u16x4*)x_bf)[i] = o;
        return;
    }
    // transpose-convert W[K=1024][N] -> Wt[N][1024], scaled
    const float* W; unsigned short* Wt; int N, lb; float scale;
    if (bid < 8448)      { W = Wq; Wt = Wqk_t;              N = 256;  lb = bid - 8192; scale = 1.f / 16.f; }
    else if (bid < 8704) { W = Wk; Wt = Wqk_t + 256 * 1024; N = 256;  lb = bid - 8448; scale = 1.f; }
    else                 { W = Wv; Wt = Wv_t;               N = 1024; lb = bid - 8704; scale = 1.f; }
    int nb = N >> 5;
    int n0 = (lb % nb) * 32, k0 = (lb / nb) * 32;
    int tx = tid & 31, ty = tid >> 5;   // 32 x 8
    __shared__ float tile[32][33];
#pragma unroll
    for (int r = 0; r < 4; ++r)
        tile[ty + 8 * r][tx] = W[(size_t)(k0 + ty + 8 * r) * N + n0 + tx];
    __syncthreads();
#pragma unroll
    for (int r = 0; r < 4; ++r)
        Wt[(size_t)(n0 + ty + 8 * r) * 1024 + k0 + tx] = f2bf(tile[tx][ty + 8 * r] * scale);
}

// ---------------- GEMM (A[M,K] @ Bt[N,K]^T), bf16 in, bf16 out ----------------

#define BM 128
#define BN 128
#define BK 64

__global__ __launch_bounds__(256) void gemm_bt_bf16(
    const unsigned short* __restrict__ A, int lda,
    const unsigned short* __restrict__ Bt, int ldb,
    unsigned short* __restrict__ C, int ldc, int K)
{
    __shared__ __align__(16) unsigned short As[2][BM][BK];
    __shared__ __align__(16) unsigned short Bs[2][BM][BK];
    int tid = threadIdx.x;
    int m0 = blockIdx.y * BM, n0 = blockIdx.x * BN;
    int lane = tid & 63, wave = tid >> 6;
    int wr = (wave >> 1) * 64, wc = (wave & 1) * 64;
    int fr = lane & 15;
    int srow = tid >> 3, scol = (tid & 7) * 8;                       // linear LDS slot
    int scolg = (((tid & 7) ^ (srow & 7)) * 8);                      // swizzled global col
    int sw0 = (((lane >> 4) ^ (fr & 7)) * 8);                        // read slot, k-half 0
    f32x4 acc[4][4] = {};
    int nt = K / BK;

    const unsigned short* Ab = A + (size_t)(m0 + srow) * lda + scolg;
    const unsigned short* Bb = Bt + (size_t)(n0 + srow) * ldb + scolg;

#define STAGE_G(t, p) { \
    const unsigned short* Ap = Ab + (t) * BK; \
    const unsigned short* Bp = Bb + (t) * BK; \
    _Pragma("unroll") \
    for (int i = 0; i < 4; ++i) { \
        GLL(Ap + (size_t)32 * i * lda, &As[p][srow + 32 * i][scol]); \
        GLL(Bp + (size_t)32 * i * ldb, &Bs[p][srow + 32 * i][scol]); \
    } }

    STAGE_G(0, 0);
    STAGE_G(1, 1);
    for (int t = 0; t < nt; ++t) {
        int p = t & 1;
        if (t + 1 < nt) VM8(); else VM0();
        BAR();
#pragma unroll
        for (int ks = 0; ks < BK; ks += 32) {
            int fo = ks ? (sw0 ^ 32) : sw0;
            bf16x8 af[4], bfr[4];
#pragma unroll
            for (int i = 0; i < 4; ++i) af[i]  = *(const bf16x8*)(&As[p][wr + 16 * i + fr][fo]);
#pragma unroll
            for (int j = 0; j < 4; ++j) bfr[j] = *(const bf16x8*)(&Bs[p][wc + 16 * j + fr][fo]);
#pragma unroll
            for (int i = 0; i < 4; ++i)
#pragma unroll
                for (int j = 0; j < 4; ++j)
                    acc[i][j] = __builtin_amdgcn_mfma_f32_16x16x32_bf16(af[i], bfr[j], acc[i][j], 0, 0, 0);
        }
        BAR();
        if (t + 2 < nt) STAGE_G(t + 2, p);
    }
#pragma unroll
    for (int i = 0; i < 4; ++i)
#pragma unroll
        for (int j = 0; j < 4; ++j)
#pragma unroll
            for (int r = 0; r < 4; ++r) {
                int row = m0 + wr + 16 * i + (lane >> 4) * 4 + r;
                int col = n0 + wc + 16 * j + fr;
                C[(size_t)row * ldc + col] = f2bf(acc[i][j][r]);
            }
}

// ---------------- scores: E = exp(Q Kt^T) bf16 + partial row sums ----------------
// QK buffer: [8192][512] bf16, Q = cols 0:256, K = cols 256:512.
// Live (causal) tiles only: 544 blocks, XCD-bijective swizzle (544 = 8*68).

__global__ __launch_bounds__(256) void scores_e(
    const unsigned short* __restrict__ QK, unsigned short* __restrict__ Ebf,
    float* __restrict__ partials)
{
    int lin = blockIdx.x;                     // 0..543
    int swz = (lin & 7) * 68 + (lin >> 3);
    int b = swz / 136, t = swz - b * 136;
    int y = (int)floorf((sqrtf(8.f * (float)t + 1.f) - 1.f) * 0.5f);
    if ((y + 1) * (y + 2) / 2 <= t) ++y;
    if (y * (y + 1) / 2 > t) --y;
    int x = t - y * (y + 1) / 2;
    int m0 = y * 128, n0 = x * 128;

    const unsigned short* A  = QK + (size_t)b * 2048 * 512;
    const unsigned short* Bt = A + 256;
    unsigned short* Eb = Ebf + (size_t)b * 2048 * 2048;

    __shared__ __align__(16) unsigned short As[2][128][64];
    __shared__ __align__(16) unsigned short Bs[2][128][64];
    __shared__ float rowsum2[2][128];
    int tid = threadIdx.x;
    int lane = tid & 63, wave = tid >> 6;
    int wr = (wave >> 1) * 64, wc = (wave & 1) * 64;
    int fr = lane & 15;
    int srow = tid >> 3, scol = (tid & 7) * 8;
    int scolg = (((tid & 7) ^ (srow & 7)) * 8);
    int sw0 = (((lane >> 4) ^ (fr & 7)) * 8);
    f32x4 acc[4][4] = {};

    const unsigned short* Ab = A  + (size_t)(m0 + srow) * 512 + scolg;
    const unsigned short* Bb = Bt + (size_t)(n0 + srow) * 512 + scolg;

#define STAGE_S(t, p) { \
    const unsigned short* Ap = Ab + (t) * 64; \
    const unsigned short* Bp = Bb + (t) * 64; \
    _Pragma("unroll") \
    for (int i = 0; i < 4; ++i) { \
        GLL(Ap + (size_t)32 * i * 512, &As[p][srow + 32 * i][scol]); \
        GLL(Bp + (size_t)32 * i * 512, &Bs[p][srow + 32 * i][scol]); \
    } }

    STAGE_S(0, 0);
    STAGE_S(1, 1);
#pragma unroll
    for (int tt = 0; tt < 4; ++tt) {
        int p = tt & 1;
        if (tt < 3) VM8(); else VM0();
        BAR();
#pragma unroll
        for (int ks = 0; ks < 64; ks += 32) {
            int fo = ks ? (sw0 ^ 32) : sw0;
            bf16x8 af[4], bfr[4];
#pragma unroll
            for (int i = 0; i < 4; ++i) af[i]  = *(const bf16x8*)(&As[p][wr + 16 * i + fr][fo]);
#pragma unroll
            for (int j = 0; j < 4; ++j) bfr[j] = *(const bf16x8*)(&Bs[p][wc + 16 * j + fr][fo]);
#pragma unroll
            for (int i = 0; i < 4; ++i)
#pragma unroll
                for (int j = 0; j < 4; ++j)
                    acc[i][j] = __builtin_amdgcn_mfma_f32_16x16x32_bf16(af[i], bfr[j], acc[i][j], 0, 0, 0);
        }
        BAR();
        if (tt + 2 < 4) STAGE_S(tt + 2, p);
    }

    // exp + mask + bf16 store + per-row partial sums
#pragma unroll
    for (int i = 0; i < 4; ++i)
#pragma unroll
        for (int r = 0; r < 4; ++r) {
            int q = m0 + wr + 16 * i + (lane >> 4) * 4 + r;
            float s = 0.f;
#pragma unroll
            for (int j = 0; j < 4; ++j) {
                int k = n0 + wc + 16 * j + fr;
                float e = (k <= q) ? __expf(acc[i][j][r]) : 0.f;
                Eb[(size_t)q * 2048 + k] = f2bf(e);
                s += e;
            }
            s += __shfl_xor(s, 1, 64); s += __shfl_xor(s, 2, 64);
            s += __shfl_xor(s, 4, 64); s += __shfl_xor(s, 8, 64);
            if (fr == 0) rowsum2[wave & 1][wr + 16 * i + (lane >> 4) * 4 + r] = s;
        }
    __syncthreads();
    if (tid < 128)
        partials[((size_t)b * 2048 + m0 + tid) * 16 + x] =
            rowsum2[0][tid] + rowsum2[1][tid];
}

// ---------------- finalize: W = E*inv (fp32, zeros above diag) ----------------

__global__ __launch_bounds__(256) void finalize_w(
    const unsigned short* __restrict__ Ebf, const float* __restrict__ partials,
    float* __restrict__ Wout)
{
    int r = blockIdx.x, q = r & 2047, tid = threadIdx.x;
    __shared__ float invs;
    if (tid < 64) {
        int nt = q >> 7;
        float p = (tid <= nt) ? partials[(size_t)r * 16 + tid] : 0.f;
        p += __shfl_xor(p, 1, 64); p += __shfl_xor(p, 2, 64);
        p += __shfl_xor(p, 4, 64); p += __shfl_xor(p, 8, 64);
        if (tid == 0) invs = 1.f / p;
    }
    __syncthreads();
    float iv = invs;
    const unsigned short* er = Ebf + (size_t)r * 2048;
    float* wrow = Wout + (size_t)r * 2048;
    int c0 = tid * 8;
    f32x4 o0 = {}, o1 = {};
    if (c0 <= q) {   // masked entries within the chunk are exact bf16 zeros
        bf16x8 e = *(const bf16x8*)(er + c0);
#pragma unroll
        for (int j = 0; j < 4; ++j) {
            union { unsigned int u; float f; } a, bb;
            a.u = ((unsigned int)(unsigned short)e[j]) << 16;
            bb.u = ((unsigned int)(unsigned short)e[j + 4]) << 16;
            o0[j] = a.f * iv; o1[j] = bb.f * iv;
        }
    }
    *((f32x4*)wrow + 2 * tid) = o0;
    *((f32x4*)wrow + 2 * tid + 1) = o1;
}

// ---------------- PV: O = (E @ V) * inv, causal k-limit, XCD-balanced ----------------

__global__ __launch_bounds__(256) void gemm_pv(
    const unsigned short* __restrict__ P, const unsigned short* __restrict__ Vt,
    const float* __restrict__ partials, float* __restrict__ O)
{
    int lin = blockIdx.x;
    int j   = lin & 7;        // target XCD
    int idx = lin >> 3;       // 0..63
    int x   = idx & 7;        // col tile
    int h   = idx >> 3;       // 0..7
    int b   = h >> 1;         // batch
    int y   = (h & 1) ? j : 15 - j;   // row tile (balanced causal work)

    int m0 = y * BM, n0 = x * BN;
    const unsigned short* Pb = P + (size_t)b * 2048 * 2048;
    const unsigned short* Bt = Vt + (size_t)b * 2048;   // ldb = 8192
    float* Ob = O + (size_t)b * 2048 * 1024;
    int nt = (y + 1) * 2;     // Klim / BK, >= 2

    __shared__ __align__(16) unsigned short As[2][BM][BK];
    __shared__ __align__(16) unsigned short Bs[2][BM][BK];
    __shared__ float invsh[128];
    int tid = threadIdx.x;
    int lane = tid & 63, wave = tid >> 6;
    int wr = (wave >> 1) * 64, wc = (wave & 1) * 64;
    int fr = lane & 15;
    int srow = tid >> 3, scol = (tid & 7) * 8;
    int scolg = (((tid & 7) ^ (srow & 7)) * 8);
    int sw0 = (((lane >> 4) ^ (fr & 7)) * 8);
    f32x4 acc[4][4] = {};

    const unsigned short* Ab = Pb + (size_t)(m0 + srow) * 2048 + scolg;
    const unsigned short* Bb = Bt + (size_t)(n0 + srow) * 8192 + scolg;

#define STAGE_P(t, p) { \
    const unsigned short* Ap = Ab + (t) * BK; \
    const unsigned short* Bp = Bb + (t) * BK; \
    _Pragma("unroll") \
    for (int i = 0; i < 4; ++i) { \
        GLL(Ap + (size_t)32 * i * 2048, &As[p][srow + 32 * i][scol]); \
        GLL(Bp + (size_t)32 * i * 8192, &Bs[p][srow + 32 * i][scol]); \
    } }

    // per-row 1/sum from partials (y+1 live tiles per row, uniform in block).
    // Compiler-inserted waits drain these loads before STAGE issues.
    if (tid < 128) {
        const float* pp = partials + ((size_t)b * 2048 + m0 + tid) * 16;
        float s = 0.f;
        for (int i = 0; i <= y; ++i) s += pp[i];
        invsh[tid] = 1.f / s;
    }

    STAGE_P(0, 0);
    STAGE_P(1, 1);
    for (int t = 0; t < nt; ++t) {
        int p = t & 1;
        if (t + 1 < nt) VM8(); else VM0();
        BAR();
#pragma unroll
        for (int ks = 0; ks < BK; ks += 32) {
            int fo = ks ? (sw0 ^ 32) : sw0;
            bf16x8 af[4], bfr[4];
#pragma unroll
            for (int i = 0; i < 4; ++i) af[i]  = *(const bf16x8*)(&As[p][wr + 16 * i + fr][fo]);
#pragma unroll
            for (int jj = 0; jj < 4; ++jj) bfr[jj] = *(const bf16x8*)(&Bs[p][wc + 16 * jj + fr][fo]);
#pragma unroll
            for (int i = 0; i < 4; ++i)
#pragma unroll
                for (int jj = 0; jj < 4; ++jj)
                    acc[i][jj] = __builtin_amdgcn_mfma_f32_16x16x32_bf16(af[i], bfr[jj], acc[i][jj], 0, 0, 0);
        }
        BAR();
        if (t + 2 < nt) STAGE_P(t + 2, p);
    }
#pragma unroll
    for (int i = 0; i < 4; ++i)
#pragma unroll
        for (int r = 0; r < 4; ++r) {
            int rloc = wr + 16 * i + (lane >> 4) * 4 + r;
            int row = m0 + rloc;
            float iv = invsh[rloc];
#pragma unroll
            for (int jj = 0; jj < 4; ++jj) {
                int col = n0 + wc + 16 * jj + fr;
                Ob[(size_t)row * 1024 + col] = acc[i][jj][r] * iv;
            }
        }
}

// ---------------- launcher ----------------

extern "C" void kernel_launch(void* const* d_in, const int* in_sizes, int n_in,
                              void* d_out, int out_size, void* d_ws, size_t ws_size,
                              hipStream_t stream) {
    (void)in_sizes; (void)n_in; (void)out_size; (void)ws_size;
    const float* x  = (const float*)d_in[0];
    const float* Wq = (const float*)d_in[1];
    const float* Wk = (const float*)d_in[2];
    const float* Wv = (const float*)d_in[3];
    const int B = 4, T = 2048, D = 1024;
    const int M = B * T;  // 8192

    char* ws = (char*)d_ws;
    size_t off = 0;
    auto alloc = [&](size_t bytes) {
        void* p = ws + off; off += (bytes + 255) & ~(size_t)255; return p;
    };
    unsigned short* x_bf  = (unsigned short*)alloc((size_t)M * D * 2);
    unsigned short* Wqk_t = (unsigned short*)alloc((size_t)512 * D * 2);
    unsigned short* Wv_t  = (unsigned short*)alloc((size_t)D * D * 2);
    unsigned short* QK_bf = (unsigned short*)alloc((size_t)M * 512 * 2);
    unsigned short* Vt_bf = (unsigned short*)alloc((size_t)D * M * 2);
    unsigned short* E_bf  = (unsigned short*)alloc((size_t)M * T * 2);
    float*          parts = (float*)alloc((size_t)M * 16 * 4);

    float* outO = (float*)d_out;                       // [4][2048][1024]
    float* outW = (float*)d_out + (size_t)M * D;       // [4][2048][2048]

    // 1. prep: x->bf16 + 3 weight transposes (one launch)
    prep<<<dim3(8192 + 256 + 256 + 1024), 256, 0, stream>>>(
        x, Wq, Wk, Wv, x_bf, Wqk_t, Wv_t);

    // 2. QK-concat GEMM: [8192 x 512] = x_bf @ Wqk_t^T
    gemm_bt_bf16<<<dim3(512 / BN, M / BM), 256, 0, stream>>>(x_bf, D, Wqk_t, D, QK_bf, 512, D);
    // 2b. V^T GEMM: [1024 x 8192] = Wv_t @ x_bf^T
    gemm_bt_bf16<<<dim3(M / BN, D / BM), 256, 0, stream>>>(Wv_t, D, x_bf, D, Vt_bf, M, D);

    // 3. scores -> bf16 E (unnormalized) + partial row sums (live tiles only)
    scores_e<<<dim3(544), 256, 0, stream>>>(QK_bf, E_bf, parts);

    // 4. PV GEMM on unnormalized E, inline inv, scale in epilogue
    gemm_pv<<<dim3(512), 256, 0, stream>>>(E_bf, Vt_bf, parts, outO);

    // 5. finalize: normalized fp32 W to d_out (incl. zeros above diagonal)
    finalize_w<<<dim3(M), 256, 0, stream>>>(E_bf, parts, outW);
}

// Round 6
// 110.102 us; speedup vs baseline: 1.4913x; 1.1572x over previous
//
#include <hip/hip_runtime.h>

// CausalSelfAttention: B=4, T=2048, D=1024, DA=256, fp32 in/out.
// 4 launches: prep -> qkvt GEMM (QK [8192x512] + Vt [1024x8192] merged) ->
// scores (bf16 E + partial row sums) -> pv_fin (PV GEMM + W finalize merged).
// MFMA kernels: T4 counted-vmcnt double-buffer pipeline + T2 source-swizzled
// LDS (linear dest for global_load_lds, XOR slot on read).

typedef short bf16x8 __attribute__((ext_vector_type(8)));   // 8 bf16 in 4 VGPRs
typedef float f32x4  __attribute__((ext_vector_type(4)));
typedef unsigned int  u32x4 __attribute__((ext_vector_type(4)));
typedef unsigned short u16x4 __attribute__((ext_vector_type(4)));

static __device__ __forceinline__ unsigned short f2bf(float f) {
    union { float f; unsigned int u; } v; v.f = f;
    unsigned int u = v.u;
    return (unsigned short)((u + 0x7FFFu + ((u >> 16) & 1u)) >> 16);  // RNE
}
static __device__ __forceinline__ float bf2f(unsigned short h) {
    union { unsigned int u; float f; } v; v.u = ((unsigned int)h) << 16; return v.f;
}

// async global->LDS, 16B per lane; LDS dest must be wave-linear (lane*16).
#define GLL(g, l) __builtin_amdgcn_global_load_lds( \
    (const __attribute__((address_space(1))) void*)(g), \
    (__attribute__((address_space(3))) void*)(l), 16, 0, 0)

#define BAR() __builtin_amdgcn_s_barrier()
#define VM8() asm volatile("s_waitcnt vmcnt(8)" ::: "memory")
#define VM0() asm volatile("s_waitcnt vmcnt(0)" ::: "memory")

// ---- shared pipeline body: uses in-scope As,Bs,srow,scol,sw0,wr,wc,fr,acc ----

#define STAGE1(AB, LDA, BB, LDB, t, p) { \
    const unsigned short* Ap_ = (AB) + (size_t)(t) * 64; \
    const unsigned short* Bp_ = (BB) + (size_t)(t) * 64; \
    _Pragma("unroll") \
    for (int i_ = 0; i_ < 4; ++i_) { \
        GLL(Ap_ + (size_t)32 * i_ * (LDA), &As[p][srow + 32 * i_][scol]); \
        GLL(Bp_ + (size_t)32 * i_ * (LDB), &Bs[p][srow + 32 * i_][scol]); \
    } }

#define PIPE_MFMA(AB, LDA, BB, LDB, NT) { \
    STAGE1(AB, LDA, BB, LDB, 0, 0); \
    STAGE1(AB, LDA, BB, LDB, 1, 1); \
    for (int t = 0; t < (NT); ++t) { \
        int p = t & 1; \
        if (t + 1 < (NT)) VM8(); else VM0(); \
        BAR(); \
        _Pragma("unroll") \
        for (int ks = 0; ks < 64; ks += 32) { \
            int fo = ks ? (sw0 ^ 32) : sw0; \
            bf16x8 af[4], bfr[4]; \
            _Pragma("unroll") \
            for (int i = 0; i < 4; ++i) af[i]  = *(const bf16x8*)(&As[p][wr + 16 * i + fr][fo]); \
            _Pragma("unroll") \
            for (int j = 0; j < 4; ++j) bfr[j] = *(const bf16x8*)(&Bs[p][wc + 16 * j + fr][fo]); \
            _Pragma("unroll") \
            for (int i = 0; i < 4; ++i) \
            _Pragma("unroll") \
                for (int j = 0; j < 4; ++j) \
                    acc[i][j] = __builtin_amdgcn_mfma_f32_16x16x32_bf16(af[i], bfr[j], acc[i][j], 0, 0, 0); \
        } \
        BAR(); \
        if (t + 2 < (NT)) STAGE1(AB, LDA, BB, LDB, t + 2, p); \
    } }

#define TILE_IDS() \
    int tid = threadIdx.x; \
    int lane = tid & 63, wave = tid >> 6; \
    int wr = (wave >> 1) * 64, wc = (wave & 1) * 64; \
    int fr = lane & 15; \
    int srow = tid >> 3, scol = (tid & 7) * 8; \
    int scolg = (((tid & 7) ^ (srow & 7)) * 8); \
    int sw0 = (((lane >> 4) ^ (fr & 7)) * 8)

// ---------------- prep: x->bf16 + 3 weight transposes, one launch ----------------

__global__ __launch_bounds__(256) void prep(
    const float* __restrict__ x, const float* __restrict__ Wq,
    const float* __restrict__ Wk, const float* __restrict__ Wv,
    unsigned short* __restrict__ x_bf, unsigned short* __restrict__ Wqk_t,
    unsigned short* __restrict__ Wv_t)
{
    int bid = blockIdx.x, tid = threadIdx.x;
    if (bid < 8192) {           // convert x: 8192*256 threads * 4 elems
        int i = bid * 256 + tid;
        f32x4 v = ((const f32x4*)x)[i];
        u16x4 o;
        o[0] = f2bf(v[0]); o[1] = f2bf(v[1]); o[2] = f2bf(v[2]); o[3] = f2bf(v[3]);
        ((u16x4*)x_bf)[i] = o;
        return;
    }
    // transpose-convert W[K=1024][N] -> Wt[N][1024], scaled
    const float* W; unsigned short* Wt; int N, lb; float scale;
    if (bid < 8448)      { W = Wq; Wt = Wqk_t;              N = 256;  lb = bid - 8192; scale = 1.f / 16.f; }
    else if (bid < 8704) { W = Wk; Wt = Wqk_t + 256 * 1024; N = 256;  lb = bid - 8448; scale = 1.f; }
    else                 { W = Wv; Wt = Wv_t;               N = 1024; lb = bid - 8704; scale = 1.f; }
    int nb = N >> 5;
    int n0 = (lb % nb) * 32, k0 = (lb / nb) * 32;
    int tx = tid & 31, ty = tid >> 5;   // 32 x 8
    __shared__ float tile[32][33];
#pragma unroll
    for (int r = 0; r < 4; ++r)
        tile[ty + 8 * r][tx] = W[(size_t)(k0 + ty + 8 * r) * N + n0 + tx];
    __syncthreads();
#pragma unroll
    for (int r = 0; r < 4; ++r)
        Wt[(size_t)(n0 + ty + 8 * r) * 1024 + k0 + tx] = f2bf(tile[tx][ty + 8 * r] * scale);
}

// ---------------- qkvt: QK-concat GEMM + V^T GEMM in one launch ----------------
// blocks 0..511:   Vt [1024 x 8192] = Wv_t @ x_bf^T   (8 x 64 tile grid)
// blocks 512..767: QK [8192 x 512]  = x_bf @ Wqk_t^T  (64 x 4 tile grid)
// Both: K=1024 (nt=16), lda=ldb=1024.

__global__ __launch_bounds__(256) void gemm_qkvt(
    const unsigned short* __restrict__ x_bf,
    const unsigned short* __restrict__ Wqk_t,
    const unsigned short* __restrict__ Wv_t,
    unsigned short* __restrict__ QK_bf,
    unsigned short* __restrict__ Vt_bf)
{
    int bid = blockIdx.x;
    const unsigned short *A, *B; unsigned short* C; int ldc, m0, n0;
    if (bid < 512) {
        A = Wv_t; B = x_bf; C = Vt_bf; ldc = 8192;
        m0 = (bid >> 6) * 128; n0 = (bid & 63) * 128;
    } else {
        int b2 = bid - 512;
        A = x_bf; B = Wqk_t; C = QK_bf; ldc = 512;
        m0 = (b2 >> 2) * 128; n0 = (b2 & 3) * 128;
    }
    __shared__ __align__(16) unsigned short As[2][128][64];
    __shared__ __align__(16) unsigned short Bs[2][128][64];
    TILE_IDS();
    f32x4 acc[4][4] = {};
    const unsigned short* Ab = A + (size_t)(m0 + srow) * 1024 + scolg;
    const unsigned short* Bb = B + (size_t)(n0 + srow) * 1024 + scolg;
    PIPE_MFMA(Ab, 1024, Bb, 1024, 16);
#pragma unroll
    for (int i = 0; i < 4; ++i)
#pragma unroll
        for (int j = 0; j < 4; ++j)
#pragma unroll
            for (int r = 0; r < 4; ++r) {
                int row = m0 + wr + 16 * i + (lane >> 4) * 4 + r;
                int col = n0 + wc + 16 * j + fr;
                C[(size_t)row * ldc + col] = f2bf(acc[i][j][r]);
            }
}

// ---------------- scores: E = exp(Q Kt^T) bf16 + partial row sums ----------------
// QK buffer: [8192][512] bf16, Q = cols 0:256, K = cols 256:512.
// Live (causal) tiles only: 544 blocks, XCD-bijective swizzle (544 = 8*68).

__global__ __launch_bounds__(256) void scores_e(
    const unsigned short* __restrict__ QK, unsigned short* __restrict__ Ebf,
    float* __restrict__ partials)
{
    int lin = blockIdx.x;                     // 0..543
    int swz = (lin & 7) * 68 + (lin >> 3);
    int b = swz / 136, t = swz - b * 136;
    int y = (int)floorf((sqrtf(8.f * (float)t + 1.f) - 1.f) * 0.5f);
    if ((y + 1) * (y + 2) / 2 <= t) ++y;
    if (y * (y + 1) / 2 > t) --y;
    int x = t - y * (y + 1) / 2;
    int m0 = y * 128, n0 = x * 128;

    const unsigned short* A  = QK + (size_t)b * 2048 * 512;
    const unsigned short* Bt = A + 256;
    unsigned short* Eb = Ebf + (size_t)b * 2048 * 2048;

    __shared__ __align__(16) unsigned short As[2][128][64];
    __shared__ __align__(16) unsigned short Bs[2][128][64];
    __shared__ float rowsum2[2][128];
    TILE_IDS();
    f32x4 acc[4][4] = {};
    const unsigned short* Ab = A  + (size_t)(m0 + srow) * 512 + scolg;
    const unsigned short* Bb = Bt + (size_t)(n0 + srow) * 512 + scolg;
    PIPE_MFMA(Ab, 512, Bb, 512, 4);

    // exp + mask + bf16 store + per-row partial sums
#pragma unroll
    for (int i = 0; i < 4; ++i)
#pragma unroll
        for (int r = 0; r < 4; ++r) {
            int q = m0 + wr + 16 * i + (lane >> 4) * 4 + r;
            float s = 0.f;
#pragma unroll
            for (int j = 0; j < 4; ++j) {
                int k = n0 + wc + 16 * j + fr;
                float e = (k <= q) ? __expf(acc[i][j][r]) : 0.f;
                Eb[(size_t)q * 2048 + k] = f2bf(e);
                s += e;
            }
            s += __shfl_xor(s, 1, 64); s += __shfl_xor(s, 2, 64);
            s += __shfl_xor(s, 4, 64); s += __shfl_xor(s, 8, 64);
            if (fr == 0) rowsum2[wave & 1][wr + 16 * i + (lane >> 4) * 4 + r] = s;
        }
    __syncthreads();
    if (tid < 128)
        partials[((size_t)b * 2048 + m0 + tid) * 16 + x] =
            rowsum2[0][tid] + rowsum2[1][tid];
}

// ---------------- pv_fin: PV GEMM (blocks 0..511) + W finalize (512..2559) ----------------

__global__ __launch_bounds__(256) void pv_fin(
    const unsigned short* __restrict__ E, const unsigned short* __restrict__ Vt,
    const float* __restrict__ partials, float* __restrict__ O,
    float* __restrict__ W)
{
    int bid = blockIdx.x;
    __shared__ __align__(16) unsigned short As[2][128][64];
    __shared__ __align__(16) unsigned short Bs[2][128][64];
    __shared__ float invsh[128];

    if (bid < 512) {
        // PV: O = (E @ V) * inv, causal k-limit, XCD-balanced decode
        int j   = bid & 7;        // target XCD
        int idx = bid >> 3;       // 0..63
        int x   = idx & 7;        // col tile
        int h   = idx >> 3;       // 0..7
        int b   = h >> 1;         // batch
        int y   = (h & 1) ? j : 15 - j;   // row tile (balanced causal work)

        int m0 = y * 128, n0 = x * 128;
        const unsigned short* Pb = E + (size_t)b * 2048 * 2048;
        const unsigned short* Bt = Vt + (size_t)b * 2048;   // ldb = 8192
        float* Ob = O + (size_t)b * 2048 * 1024;
        int nt = (y + 1) * 2;     // Klim / BK, >= 2

        TILE_IDS();
        f32x4 acc[4][4] = {};

        // per-row 1/sum from partials (y+1 live tiles per row).
        // Compiler-inserted waits drain these loads before STAGE issues.
        if (tid < 128) {
            const float* pp = partials + ((size_t)b * 2048 + m0 + tid) * 16;
            float s = 0.f;
            for (int i = 0; i <= y; ++i) s += pp[i];
            invsh[tid] = 1.f / s;
        }

        const unsigned short* Ab = Pb + (size_t)(m0 + srow) * 2048 + scolg;
        const unsigned short* Bb = Bt + (size_t)(n0 + srow) * 8192 + scolg;
        PIPE_MFMA(Ab, 2048, Bb, 8192, nt);
#pragma unroll
        for (int i = 0; i < 4; ++i)
#pragma unroll
            for (int r = 0; r < 4; ++r) {
                int rloc = wr + 16 * i + (lane >> 4) * 4 + r;
                float iv = invsh[rloc];
#pragma unroll
                for (int jj = 0; jj < 4; ++jj)
                    Ob[(size_t)(m0 + rloc) * 1024 + n0 + wc + 16 * jj + fr] = acc[i][jj][r] * iv;
            }
        return;
    }

    // finalize: 4 rows per block, one row per wave; W = E*inv, zeros above diag.
    int tid = threadIdx.x;
    int wave = tid >> 6, lane = tid & 63;
    int r = (bid - 512) * 4 + wave;       // 0..8191
    int q = r & 2047;
    float p = (lane < 16 && lane <= (q >> 7)) ? partials[(size_t)r * 16 + lane] : 0.f;
    p += __shfl_xor(p, 1, 64); p += __shfl_xor(p, 2, 64);
    p += __shfl_xor(p, 4, 64); p += __shfl_xor(p, 8, 64);
    float iv = 1.f / __shfl(p, 0, 64);
    const unsigned short* er = E + (size_t)r * 2048;
    float* wrow = W + (size_t)r * 2048;
#pragma unroll
    for (int cc = 0; cc < 4; ++cc) {
        int c0 = lane * 8 + cc * 512;
        f32x4 o0 = {}, o1 = {};
        if (c0 <= q) {   // masked entries within a live chunk are exact bf16 zeros
            bf16x8 e = *(const bf16x8*)(er + c0);
#pragma unroll
            for (int j = 0; j < 4; ++j) {
                o0[j] = bf2f((unsigned short)e[j]) * iv;
                o1[j] = bf2f((unsigned short)e[j + 4]) * iv;
            }
        }
        *((f32x4*)(wrow + c0)) = o0;
        *((f32x4*)(wrow + c0) + 1) = o1;
    }
}

// ---------------- launcher ----------------

extern "C" void kernel_launch(void* const* d_in, const int* in_sizes, int n_in,
                              void* d_out, int out_size, void* d_ws, size_t ws_size,
                              hipStream_t stream) {
    (void)in_sizes; (void)n_in; (void)out_size; (void)ws_size;
    const float* x  = (const float*)d_in[0];
    const float* Wq = (const float*)d_in[1];
    const float* Wk = (const float*)d_in[2];
    const float* Wv = (const float*)d_in[3];
    const int B = 4, T = 2048, D = 1024;
    const int M = B * T;  // 8192

    char* ws = (char*)d_ws;
    size_t off = 0;
    auto alloc = [&](size_t bytes) {
        void* p = ws + off; off += (bytes + 255) & ~(size_t)255; return p;
    };
    unsigned short* x_bf  = (unsigned short*)alloc((size_t)M * D * 2);
    unsigned short* Wqk_t = (unsigned short*)alloc((size_t)512 * D * 2);
    unsigned short* Wv_t  = (unsigned short*)alloc((size_t)D * D * 2);
    unsigned short* QK_bf = (unsigned short*)alloc((size_t)M * 512 * 2);
    unsigned short* Vt_bf = (unsigned short*)alloc((size_t)D * M * 2);
    unsigned short* E_bf  = (unsigned short*)alloc((size_t)M * T * 2);
    float*          parts = (float*)alloc((size_t)M * 16 * 4);

    float* outO = (float*)d_out;                       // [4][2048][1024]
    float* outW = (float*)d_out + (size_t)M * D;       // [4][2048][2048]

    // 1. prep: x->bf16 + 3 weight transposes
    prep<<<dim3(8192 + 256 + 256 + 1024), 256, 0, stream>>>(
        x, Wq, Wk, Wv, x_bf, Wqk_t, Wv_t);

    // 2. QK GEMM + Vt GEMM merged (independent; 768 blocks fills machine)
    gemm_qkvt<<<dim3(768), 256, 0, stream>>>(x_bf, Wqk_t, Wv_t, QK_bf, Vt_bf);

    // 3. scores -> bf16 E (unnormalized) + partial row sums (live tiles only)
    scores_e<<<dim3(544), 256, 0, stream>>>(QK_bf, E_bf, parts);

    // 4. PV GEMM + W finalize merged (independent given scores)
    pv_fin<<<dim3(512 + 2048), 256, 0, stream>>>(E_bf, Vt_bf, parts, outO, outW);
}